// Round 2
// baseline (541.155 us; speedup 1.0000x reference)
//
#include <hip/hip_runtime.h>
#include <hip/hip_bf16.h>

#define NN 6144
#define DD 128
#define INV_TAU 10.0f
#define KJ 64          // adjacency cols per iteration
#define NIT 12         // iterations per block  -> 768 cols per block
#define NJC 8          // col-chunks per row-tile (8*768 = 6144)

typedef __attribute__((ext_vector_type(4))) float f32x4;
typedef __attribute__((ext_vector_type(8))) short s16x8;

__device__ __forceinline__ void ld4_async(const float4* p, float4& d) {
    asm volatile("global_load_dwordx4 %0, %1, off" : "=v"(d) : "v"(p));
}
__device__ __forceinline__ void vm_wait0() {
    asm volatile("s_waitcnt vmcnt(0)" ::: "memory");
    __builtin_amdgcn_sched_barrier(0);   // rule#18: no reg-op hoist past the wait
}

// ---- Kernel 1: L2-normalized bf16 copies, raw-transposed bf16, W1^T -------
// y=0..2: normalize F/M/P -> Fnb/Mnb/Pnb ; y=3: W1 -> W1tb ;
// y=4: embM -> EbTM (bf16, [128][6144]) ; y=5: embP -> EbTP
__global__ void k_normalize(const float* __restrict__ embF,
                            const float* __restrict__ embM,
                            const float* __restrict__ embP,
                            const float* __restrict__ W1,
                            __hip_bfloat16* __restrict__ Fnb,
                            __hip_bfloat16* __restrict__ Mnb,
                            __hip_bfloat16* __restrict__ Pnb,
                            __hip_bfloat16* __restrict__ EbTM,
                            __hip_bfloat16* __restrict__ EbTP,
                            __hip_bfloat16* __restrict__ W1tb) {
    __shared__ float T[64][67];
    const int which = blockIdx.y;
    const int tid = threadIdx.x;
    if (which == 3) {                 // W1 (256x128) -> bf16 W1^T (128x256)
        if (blockIdx.x < 128) {
            int n = blockIdx.x, c = tid;
            W1tb[n * 256 + c] = __float2bfloat16(W1[c * DD + n]);
        }
        return;
    }
    if (which >= 4) {                 // raw transpose: emb[j][d] -> EbT[d][j]
        if (blockIdx.x >= 192) return;
        const float* src = (which == 4) ? embM : embP;
        __hip_bfloat16* dst = (which == 4) ? EbTM : EbTP;
        const int jt = (blockIdx.x % 96) * 64, dt = (blockIdx.x / 96) * 64;
#pragma unroll
        for (int u = 0; u < 4; ++u) {
            int idx = u * 256 + tid;
            int r = idx >> 4, c4 = idx & 15;
            float4 v = *reinterpret_cast<const float4*>(
                src + (size_t)(jt + r) * DD + dt + c4 * 4);
            T[r][c4 * 4 + 0] = v.x; T[r][c4 * 4 + 1] = v.y;
            T[r][c4 * 4 + 2] = v.z; T[r][c4 * 4 + 3] = v.w;
        }
        __syncthreads();
#pragma unroll
        for (int u = 0; u < 8; ++u) {
            int idx = u * 256 + tid;
            int d = idx >> 5, jj = (idx & 31) * 2;
            __hip_bfloat162 o;
            o.x = __float2bfloat16(T[jj][d]);
            o.y = __float2bfloat16(T[jj + 1][d]);
            *reinterpret_cast<__hip_bfloat162*>(
                dst + (size_t)(dt + d) * NN + jt + jj) = o;
        }
        return;
    }
    const float* src = which == 0 ? embF : (which == 1 ? embM : embP);
    __hip_bfloat16* dstb = which == 0 ? Fnb : (which == 1 ? Mnb : Pnb);
    int wave = tid >> 6, lane = tid & 63;
    int row = blockIdx.x * 4 + wave;
    float2 v = reinterpret_cast<const float2*>(src + (size_t)row * DD)[lane];
    float s = v.x * v.x + v.y * v.y;
#pragma unroll
    for (int m = 1; m <= 32; m <<= 1) s += __shfl_xor(s, m);
    float inv = 1.0f / fmaxf(sqrtf(s), 1e-12f);
    __hip_bfloat162 ob;
    ob.x = __float2bfloat16(v.x * inv);
    ob.y = __float2bfloat16(v.y * inv);
    reinterpret_cast<__hip_bfloat162*>(dstb + (size_t)row * DD)[lane] = ob;
}

// ------- Kernel 2: single dense streaming pass over the adjacency ----------
// per block: 128 rows x 768 cols of one adjacency half.
// per 64-col chunk: sim = Fnb@Mnb^T (MFMA) -> exp -> tot/pos/cnt (masked);
//                   repr += adj(bf16) @ embX (MFMA, B from EbT) in registers.
// repr merged across col-chunk blocks via packed-bf16 global atomics.
__global__ __launch_bounds__(256, 2) void k_main(
        const float* __restrict__ FM_adj, const float* __restrict__ FP_adj,
        const __hip_bfloat16* __restrict__ Fnb,
        const __hip_bfloat16* __restrict__ Mnb,
        const __hip_bfloat16* __restrict__ Pnb,
        const __hip_bfloat16* __restrict__ EbTM,
        const __hip_bfloat16* __restrict__ EbTP,
        __hip_bfloat16* __restrict__ reprB,
        float* __restrict__ FMpos, float* __restrict__ FPpos,
        float* __restrict__ FMtot, float* __restrict__ FPtot,
        float* __restrict__ cntF, float* __restrict__ cntP) {
    // strides: 72 bf16 = 144B (36 dw = 4 mod 32 -> 2-way, free);
    //          136 bf16 = 272B (68 dw = 4 mod 32) matches proven PBL pattern.
    __shared__ __hip_bfloat16 AdjS[128][72];
    __shared__ __hip_bfloat16 MnbS[64][136];
    __shared__ __hip_bfloat16 EbTS[128][72];

    const int b = blockIdx.x;
    const int swz = (b & 7) * 96 + (b >> 3);          // bijective XCD chunking
    const int half = swz >= 384 ? 1 : 0;
    const int s2 = swz - half * 384;
    const int jcb = s2 / 48, rt = s2 - jcb * 48;
    const float* adj = half ? FP_adj : FM_adj;
    const __hip_bfloat16* Bn = half ? Pnb : Mnb;
    const __hip_bfloat16* ET = half ? EbTP : EbTM;
    const int row0 = rt * 128;
    const int jbase = jcb * (KJ * NIT);

    const int tid = threadIdx.x, w = tid >> 6, l = tid & 63;
    const int m = l & 15, q = l >> 4;

    // A1: Fnb fragments (32 rows per wave), held for the whole kernel
    s16x8 a1[2][4];
#pragma unroll
    for (int g = 0; g < 2; ++g)
#pragma unroll
        for (int ks = 0; ks < 4; ++ks)
            a1[g][ks] = *reinterpret_cast<const s16x8*>(
                Fnb + (size_t)(row0 + w * 32 + g * 16 + m) * DD + ks * 32 + q * 8);

    f32x4 racc[2][8];
#pragma unroll
    for (int g = 0; g < 2; ++g)
#pragma unroll
        for (int n = 0; n < 8; ++n)
            racc[g][n] = (f32x4){0.f, 0.f, 0.f, 0.f};
    float tot[2][4] = {{0.f,0.f,0.f,0.f},{0.f,0.f,0.f,0.f}};
    float pos[2][4] = {{0.f,0.f,0.f,0.f},{0.f,0.f,0.f,0.f}};
    float cnt[2][4] = {{0.f,0.f,0.f,0.f},{0.f,0.f,0.f,0.f}};

    float4 av[8];
    const float* adjb = adj + (size_t)row0 * NN + jbase;
    auto issue_adj = [&](int it) {
#pragma unroll
        for (int u = 0; u < 8; ++u) {
            int idx = u * 256 + tid;
            int r = idx >> 4, c = idx & 15;
            ld4_async(reinterpret_cast<const float4*>(
                          adjb + (size_t)r * NN + it * KJ) + c, av[u]);
        }
    };
    issue_adj(0);

    for (int it = 0; it < NIT; ++it) {
        vm_wait0();                    // adj chunk in regs
        __syncthreads();               // prev compute done with LDS
        const int j0 = jbase + it * KJ;
        float4 bv[4], ev[4];
#pragma unroll
        for (int u = 0; u < 4; ++u) {  // Mnb chunk (L2-hot), fly under cvt
            int idx = u * 256 + tid;
            int r = idx >> 4, c = idx & 15;
            ld4_async(reinterpret_cast<const float4*>(
                          Bn + (size_t)(j0 + r) * DD) + c, bv[u]);
        }
#pragma unroll
        for (int u = 0; u < 4; ++u) {  // EbT chunk (L2-hot)
            int idx = u * 256 + tid;
            int r = idx >> 3, c = idx & 7;
            ld4_async(reinterpret_cast<const float4*>(
                          ET + (size_t)r * NN + j0) + c, ev[u]);
        }
#pragma unroll
        for (int u = 0; u < 8; ++u) {  // adj fp32 -> bf16 stash
            int idx = u * 256 + tid;
            int r = idx >> 4, c = idx & 15;
            __hip_bfloat16* dp = &AdjS[r][c * 4];
            dp[0] = __float2bfloat16(av[u].x);
            dp[1] = __float2bfloat16(av[u].y);
            dp[2] = __float2bfloat16(av[u].z);
            dp[3] = __float2bfloat16(av[u].w);
        }
        vm_wait0();
#pragma unroll
        for (int u = 0; u < 4; ++u) {
            int idx = u * 256 + tid;
            int r = idx >> 4, c = idx & 15;
            *reinterpret_cast<float4*>(&MnbS[r][c * 8]) = bv[u];
        }
#pragma unroll
        for (int u = 0; u < 4; ++u) {
            int idx = u * 256 + tid;
            int r = idx >> 3, c = idx & 7;
            *reinterpret_cast<float4*>(&EbTS[r][c * 8]) = ev[u];
        }
        __syncthreads();
        if (it + 1 < NIT) issue_adj(it + 1);

        // ---- sim + exp + mask (tot / pos / cnt) ----
#pragma unroll
        for (int t = 0; t < 4; ++t) {
            s16x8 b1[4];
#pragma unroll
            for (int ks = 0; ks < 4; ++ks)
                b1[ks] = *reinterpret_cast<const s16x8*>(
                    &MnbS[t * 16 + m][ks * 32 + q * 8]);
#pragma unroll
            for (int g = 0; g < 2; ++g) {
                f32x4 acc = {0.f, 0.f, 0.f, 0.f};
#pragma unroll
                for (int ks = 0; ks < 4; ++ks)
                    acc = __builtin_amdgcn_mfma_f32_16x16x32_bf16(
                        a1[g][ks], b1[ks], acc, 0, 0, 0);
#pragma unroll
                for (int r = 0; r < 4; ++r) {
                    float e = __expf(acc[r] * INV_TAU);
                    float avv = __bfloat162float(
                        AdjS[w * 32 + g * 16 + q * 4 + r][t * 16 + m]);
                    tot[g][r] += e;
                    pos[g][r] += avv * e;
                    cnt[g][r] += avv;
                }
            }
        }
        // ---- repr += adj @ embX ----
        s16x8 a2[2][2];
#pragma unroll
        for (int g = 0; g < 2; ++g)
#pragma unroll
            for (int k2 = 0; k2 < 2; ++k2)
                a2[g][k2] = *reinterpret_cast<const s16x8*>(
                    &AdjS[w * 32 + g * 16 + m][k2 * 32 + q * 8]);
#pragma unroll
        for (int n = 0; n < 8; ++n) {
            s16x8 b2a = *reinterpret_cast<const s16x8*>(&EbTS[n * 16 + m][q * 8]);
            s16x8 b2b = *reinterpret_cast<const s16x8*>(&EbTS[n * 16 + m][32 + q * 8]);
            racc[0][n] = __builtin_amdgcn_mfma_f32_16x16x32_bf16(a2[0][0], b2a, racc[0][n], 0, 0, 0);
            racc[1][n] = __builtin_amdgcn_mfma_f32_16x16x32_bf16(a2[1][0], b2a, racc[1][n], 0, 0, 0);
            racc[0][n] = __builtin_amdgcn_mfma_f32_16x16x32_bf16(a2[0][1], b2b, racc[0][n], 0, 0, 0);
            racc[1][n] = __builtin_amdgcn_mfma_f32_16x16x32_bf16(a2[1][1], b2b, racc[1][n], 0, 0, 0);
        }
    }

    // ---- epilogue: reduce over the 16 col-lanes, atomic merge ----
#pragma unroll
    for (int msk = 1; msk <= 8; msk <<= 1)
#pragma unroll
        for (int g = 0; g < 2; ++g)
#pragma unroll
            for (int r = 0; r < 4; ++r) {
                tot[g][r] += __shfl_xor(tot[g][r], msk);
                pos[g][r] += __shfl_xor(pos[g][r], msk);
                cnt[g][r] += __shfl_xor(cnt[g][r], msk);
            }
    if (m == 0) {
        float* TOT = half ? FPtot : FMtot;
        float* POS = half ? FPpos : FMpos;
        float* CNT = half ? cntP : cntF;
#pragma unroll
        for (int g = 0; g < 2; ++g)
#pragma unroll
            for (int r = 0; r < 4; ++r) {
                int row = row0 + w * 32 + g * 16 + q * 4 + r;
                atomicAdd(&TOT[row], tot[g][r]);
                atomicAdd(&POS[row], pos[g][r]);
                atomicAdd(&CNT[row], cnt[g][r]);
            }
    }
    // repr: pair adjacent d-columns across even/odd lanes -> pk-bf16 atomic
    __hip_bfloat16* rbase = reprB + half * DD;
#pragma unroll
    for (int g = 0; g < 2; ++g)
#pragma unroll
        for (int n = 0; n < 8; ++n)
#pragma unroll
            for (int r = 0; r < 4; ++r) {
                float v = racc[g][n][r];
                float vp = __shfl_xor(v, 1);
                if ((m & 1) == 0) {
                    union { unsigned u; __hip_bfloat162 h; } pk;
                    pk.h.x = __float2bfloat16(v);
                    pk.h.y = __float2bfloat16(vp);
                    const int row = row0 + w * 32 + g * 16 + q * 4 + r;
                    __hip_bfloat16* p = rbase + (size_t)row * 256 + n * 16 + m;
                    asm volatile("global_atomic_pk_add_bf16 %0, %1, off"
                                 :: "v"(p), "v"(pk.u) : "memory");
                }
            }
}

// ------- Kernel 3: MLP from bf16 repr partials (divide + repack on the fly) -
__global__ __launch_bounds__(256) void k_mlp2(
        const __hip_bfloat16* __restrict__ reprB,
        const float* __restrict__ cntF, const float* __restrict__ cntP,
        const __hip_bfloat16* __restrict__ W1tb,
        const float* __restrict__ b1, const float* __restrict__ W2,
        float* __restrict__ z) {
    const int tid = threadIdx.x, w = tid >> 6, lane = tid & 63;
    const int m = lane & 15, q = lane >> 4;
    const int unit = blockIdx.x * 4 + w;             // 0..3071
    const int rb = (unit >> 3) * 16, n0 = (unit & 7) * 16;
    const int row = rb + m;
    const float invF = 1.0f / fmaxf(cntF[row], 1.0f);
    const float invP = 1.0f / fmaxf(cntP[row], 1.0f);
    const __hip_bfloat16* rrow = reprB + (size_t)row * 256;
    f32x4 acc = {0.f, 0.f, 0.f, 0.f};
#pragma unroll
    for (int ks = 0; ks < 8; ++ks) {
        const int k0 = ks * 32 + q * 8;
        const float inv = (k0 < 128) ? invF : invP;
        union { s16x8 v; __hip_bfloat16 h[8]; } ua, ub;
        ub.v = *reinterpret_cast<const s16x8*>(rrow + k0);
#pragma unroll
        for (int e = 0; e < 8; ++e)
            ua.h[e] = __float2bfloat16(__bfloat162float(ub.h[e]) * inv);
        s16x8 bb = *reinterpret_cast<const s16x8*>(
            W1tb + (size_t)(n0 + m) * 256 + k0);
        acc = __builtin_amdgcn_mfma_f32_16x16x32_bf16(ua.v, bb, acc, 0, 0, 0);
    }
    const int n = n0 + m;
    float bias = b1[n], w20 = W2[2 * n], w21 = W2[2 * n + 1];
#pragma unroll
    for (int r = 0; r < 4; ++r) {
        float h = fmaxf(acc[r] + bias, 0.f);
        float p0 = h * w20, p1 = h * w21;
#pragma unroll
        for (int msk = 1; msk <= 8; msk <<= 1) {
            p0 += __shfl_xor(p0, msk);
            p1 += __shfl_xor(p1, msk);
        }
        if (m == 0) {
            int orow = rb + q * 4 + r;
            atomicAdd(&z[2 * orow], p0);
            atomicAdd(&z[2 * orow + 1], p1);
        }
    }
}

// ------- Kernel 4: softmax weights + loss (one atomic per block) -----------
__global__ void k_loss(const float* __restrict__ z, const float* __restrict__ b2,
                       const float* __restrict__ FMpos, const float* __restrict__ FPpos,
                       const float* __restrict__ FMtot, const float* __restrict__ FPtot,
                       const float* __restrict__ cntF, const float* __restrict__ cntP,
                       float* __restrict__ out) {
    __shared__ float red[4];
    const int tid = threadIdx.x;
    const int lane = tid & 63, wv = tid >> 6;
    const int row = blockIdx.x * 256 + tid;
    float z0 = z[row * 2] + b2[0], z1 = z[row * 2 + 1] + b2[1];
    float mx = fmaxf(z0, z1);
    float e0 = expf(z0 - mx), e1 = expf(z1 - mx);
    float inv = 1.0f / (e0 + e1);
    float w0 = e0 * inv, w1 = e1 * inv;
    out[1 + row * 2 + 0] = w0;
    out[1 + row * 2 + 1] = w1;
    float wp = w0 * FMpos[row] + w1 * FPpos[row];
    float wn = w0 * (FMtot[row] - FMpos[row]) + w1 * (FPtot[row] - FPpos[row]);
    float nei = fmaxf(cntF[row] + cntP[row], 1.0f);
    float ratio = wp / (wp + wn) / nei;
    ratio = fmaxf(ratio, 1e-10f);
    float term = -logf(ratio);
#pragma unroll
    for (int msk = 1; msk <= 32; msk <<= 1) term += __shfl_xor(term, msk);
    if (lane == 0) red[wv] = term;
    __syncthreads();
    if (tid == 0)
        atomicAdd(out, (red[0] + red[1] + red[2] + red[3]) * (1.0f / NN));
}

extern "C" void kernel_launch(void* const* d_in, const int* in_sizes, int n_in,
                              void* d_out, int out_size, void* d_ws, size_t ws_size,
                              hipStream_t stream) {
    const float* embF   = (const float*)d_in[0];
    const float* embM   = (const float*)d_in[1];
    const float* embP   = (const float*)d_in[2];
    const float* FM_adj = (const float*)d_in[3];
    const float* FP_adj = (const float*)d_in[4];
    const float* W1     = (const float*)d_in[5];
    const float* b1     = (const float*)d_in[6];
    const float* W2     = (const float*)d_in[7];
    const float* b2     = (const float*)d_in[8];
    float* out = (float*)d_out;

    // workspace layout -- total 11,272,192 B (< proven 11,321,344 B budget)
    float* ws = (float*)d_ws;
    float* FMtot = ws;                         // N   (atomic)
    float* FPtot = FMtot + NN;                 // N   (atomic)
    float* zbuf  = FPtot + NN;                 // 2N  (atomic)
    float* FMpos = zbuf + 2 * NN;              // N   (atomic)
    float* FPpos = FMpos + NN;                 // N   (atomic)
    float* cntF  = FPpos + NN;                 // N   (atomic)
    float* cntP  = cntF + NN;                  // N   (atomic)
    __hip_bfloat16* reprB = (__hip_bfloat16*)(cntP + NN);  // N*256 bf16 (atomic)
    __hip_bfloat16* Fnb  = reprB + (size_t)NN * 256;
    __hip_bfloat16* Mnb  = Fnb + (size_t)NN * DD;
    __hip_bfloat16* Pnb  = Mnb + (size_t)NN * DD;
    __hip_bfloat16* EbTM = Pnb + (size_t)NN * DD;
    __hip_bfloat16* EbTP = EbTM + (size_t)NN * DD;
    __hip_bfloat16* W1tb = EbTP + (size_t)NN * DD;

    hipMemsetAsync(ws, 0, (size_t)8 * NN * sizeof(float)
                           + (size_t)NN * 256 * sizeof(__hip_bfloat16), stream);
    hipMemsetAsync(d_out, 0, sizeof(float), stream);

    k_normalize<<<dim3(1536, 6), 256, 0, stream>>>(embF, embM, embP, W1,
                                                   Fnb, Mnb, Pnb,
                                                   EbTM, EbTP, W1tb);
    k_main<<<dim3(48 * NJC * 2), 256, 0, stream>>>(FM_adj, FP_adj,
                                                   Fnb, Mnb, Pnb, EbTM, EbTP,
                                                   reprB,
                                                   FMpos, FPpos, FMtot, FPtot,
                                                   cntF, cntP);
    k_mlp2<<<dim3(768), 256, 0, stream>>>(reprB, cntF, cntP, W1tb, b1, W2, zbuf);
    k_loss<<<dim3(NN / 256), 256, 0, stream>>>(zbuf, b2, FMpos, FPpos,
                                               FMtot, FPtot, cntF, cntP, out);
}

// Round 3
// 383.330 us; speedup vs baseline: 1.4117x; 1.4117x over previous
//
#include <hip/hip_runtime.h>
#include <hip/hip_bf16.h>

#define NN 6144
#define DD 128
#define INV_TAU 10.0f
#define KJ 64          // adjacency cols per iteration
#define NIT 24         // iterations per block  -> 1536 cols per block
#define RJCB 4         // col-chunks per row-tile (4*1536 = 6144)

typedef __attribute__((ext_vector_type(4))) float f32x4;
typedef __attribute__((ext_vector_type(8))) short s16x8;

__device__ __forceinline__ void ld4_async(const float4* p, float4& d) {
    asm volatile("global_load_dwordx4 %0, %1, off" : "=v"(d) : "v"(p));
}
__device__ __forceinline__ void vm_wait0() {
    asm volatile("s_waitcnt vmcnt(0)" ::: "memory");
    __builtin_amdgcn_sched_barrier(0);   // rule#18: no hoist past the wait
}

// ---- Kernel 1: L2-normalized bf16 copies, raw-transposed bf16, W1^T -------
// y=0..2: normalize F/M/P -> Fnb/Mnb/Pnb ; y=3: W1 -> W1tb ;
// y=4: embM -> EbTM (bf16, [128][6144]) ; y=5: embP -> EbTP
__global__ void k_normalize(const float* __restrict__ embF,
                            const float* __restrict__ embM,
                            const float* __restrict__ embP,
                            const float* __restrict__ W1,
                            __hip_bfloat16* __restrict__ Fnb,
                            __hip_bfloat16* __restrict__ Mnb,
                            __hip_bfloat16* __restrict__ Pnb,
                            __hip_bfloat16* __restrict__ EbTM,
                            __hip_bfloat16* __restrict__ EbTP,
                            __hip_bfloat16* __restrict__ W1tb) {
    __shared__ float T[64][67];
    const int which = blockIdx.y;
    const int tid = threadIdx.x;
    if (which == 3) {                 // W1 (256x128) -> bf16 W1^T (128x256)
        if (blockIdx.x < 128) {
            int n = blockIdx.x, c = tid;
            W1tb[n * 256 + c] = __float2bfloat16(W1[c * DD + n]);
        }
        return;
    }
    if (which >= 4) {                 // raw transpose: emb[j][d] -> EbT[d][j]
        if (blockIdx.x >= 192) return;
        const float* src = (which == 4) ? embM : embP;
        __hip_bfloat16* dst = (which == 4) ? EbTM : EbTP;
        const int jt = (blockIdx.x % 96) * 64, dt = (blockIdx.x / 96) * 64;
#pragma unroll
        for (int u = 0; u < 4; ++u) {
            int idx = u * 256 + tid;
            int r = idx >> 4, c4 = idx & 15;
            float4 v = *reinterpret_cast<const float4*>(
                src + (size_t)(jt + r) * DD + dt + c4 * 4);
            T[r][c4 * 4 + 0] = v.x; T[r][c4 * 4 + 1] = v.y;
            T[r][c4 * 4 + 2] = v.z; T[r][c4 * 4 + 3] = v.w;
        }
        __syncthreads();
#pragma unroll
        for (int u = 0; u < 8; ++u) {
            int idx = u * 256 + tid;
            int d = idx >> 5, jj = (idx & 31) * 2;
            __hip_bfloat162 o;
            o.x = __float2bfloat16(T[jj][d]);
            o.y = __float2bfloat16(T[jj + 1][d]);
            *reinterpret_cast<__hip_bfloat162*>(
                dst + (size_t)(dt + d) * NN + jt + jj) = o;
        }
        return;
    }
    const float* src = which == 0 ? embF : (which == 1 ? embM : embP);
    __hip_bfloat16* dstb = which == 0 ? Fnb : (which == 1 ? Mnb : Pnb);
    int wave = tid >> 6, lane = tid & 63;
    int row = blockIdx.x * 4 + wave;
    float2 v = reinterpret_cast<const float2*>(src + (size_t)row * DD)[lane];
    float s = v.x * v.x + v.y * v.y;
#pragma unroll
    for (int m = 1; m <= 32; m <<= 1) s += __shfl_xor(s, m);
    float inv = 1.0f / fmaxf(sqrtf(s), 1e-12f);
    __hip_bfloat162 ob;
    ob.x = __float2bfloat16(v.x * inv);
    ob.y = __float2bfloat16(v.y * inv);
    reinterpret_cast<__hip_bfloat162*>(dstb + (size_t)row * DD)[lane] = ob;
}

// ------- Kernel 2: dense streaming pass over the adjacency -----------------
// block = 64 rows x 1536 cols of one half; wave owns 16 rows (M=16).
// per 64-col chunk: sim = Fnb@Mnb^T -> exp -> tot/pos/cnt (masked);
//                   repr += adj(bf16)@embX (MFMA, B from EbT) in registers.
// All of {adj, Mn, EbT} prefetched one iteration ahead into registers.
__global__ __launch_bounds__(256, 3) void k_main(
        const float* __restrict__ FM_adj, const float* __restrict__ FP_adj,
        const __hip_bfloat16* __restrict__ Fnb,
        const __hip_bfloat16* __restrict__ Mnb,
        const __hip_bfloat16* __restrict__ Pnb,
        const __hip_bfloat16* __restrict__ EbTM,
        const __hip_bfloat16* __restrict__ EbTP,
        __hip_bfloat16* __restrict__ reprB,
        float* __restrict__ FMpos, float* __restrict__ FPpos,
        float* __restrict__ FMtot, float* __restrict__ FPtot,
        float* __restrict__ cntF, float* __restrict__ cntP) {
    __shared__ __hip_bfloat16 AdjS[4][16][72];      //  9,216 B (wave-private)
    __shared__ __hip_bfloat16 MnS[64][136];         // 17,408 B
    __shared__ __hip_bfloat16 EbTS[128][72];        // 18,432 B  -> 45,056 total

    // identity mapping: consecutive blocks -> distinct row-tiles (staggers the
    // repr merge; round-2's swizzle co-scheduled 8 same-rt writers -> ping-pong)
    const int b = blockIdx.x;
    const int rt = b % 96, tmp = b / 96;
    const int jcb = tmp & 3, half = tmp >> 2;
    const float* adj = half ? FP_adj : FM_adj;
    const __hip_bfloat16* Bn = half ? Pnb : Mnb;
    const __hip_bfloat16* ET = half ? EbTP : EbTM;
    const int row0 = rt * 64;
    const int jbase = jcb * (KJ * NIT);

    const int tid = threadIdx.x, w = tid >> 6, l = tid & 63;
    const int m = l & 15, q = l >> 4;

    // A1: Fnb fragments for this wave's 16 rows, held for the whole kernel
    s16x8 a1[4];
#pragma unroll
    for (int ks = 0; ks < 4; ++ks)
        a1[ks] = *reinterpret_cast<const s16x8*>(
            Fnb + (size_t)(row0 + w * 16 + m) * DD + ks * 32 + q * 8);

    f32x4 racc[8];
#pragma unroll
    for (int n = 0; n < 8; ++n) racc[n] = (f32x4){0.f, 0.f, 0.f, 0.f};
    float tot[4] = {0.f, 0.f, 0.f, 0.f};
    float pos[4] = {0.f, 0.f, 0.f, 0.f};
    float cnt[4] = {0.f, 0.f, 0.f, 0.f};

    float4 av[4], bv[4], ev[4];
    const float* adjw = adj + (size_t)(row0 + w * 16) * NN + jbase;
    auto issue = [&](int it) {
#pragma unroll
        for (int u = 0; u < 4; ++u) {          // this wave's 16x64 adj tile
            int idx = u * 64 + l;
            int r = idx >> 4, c = idx & 15;
            ld4_async(reinterpret_cast<const float4*>(
                          adjw + (size_t)r * NN + it * KJ) + c, av[u]);
        }
#pragma unroll
        for (int u = 0; u < 4; ++u) {          // Mnb chunk (block-wide)
            int idx = u * 256 + tid;
            int r = idx >> 4, c = idx & 15;
            ld4_async(reinterpret_cast<const float4*>(
                          Bn + (size_t)(jbase + it * KJ + r) * DD) + c, bv[u]);
        }
#pragma unroll
        for (int u = 0; u < 4; ++u) {          // EbT chunk (block-wide)
            int idx = u * 256 + tid;
            int r = idx >> 3, c = idx & 7;
            ld4_async(reinterpret_cast<const float4*>(
                          ET + (size_t)r * NN + jbase + it * KJ) + c, ev[u]);
        }
    };
    issue(0);

    for (int it = 0; it < NIT; ++it) {
        vm_wait0();                    // regs for it (issued last iter) ready
        __syncthreads();               // prev compute done with LDS
#pragma unroll
        for (int u = 0; u < 4; ++u) {  // adj fp32 -> bf16, wave-private stash
            int idx = u * 64 + l;
            int r = idx >> 4, c = idx & 15;
            __hip_bfloat16* dp = &AdjS[w][r][c * 4];
            dp[0] = __float2bfloat16(av[u].x);
            dp[1] = __float2bfloat16(av[u].y);
            dp[2] = __float2bfloat16(av[u].z);
            dp[3] = __float2bfloat16(av[u].w);
        }
#pragma unroll
        for (int u = 0; u < 4; ++u) {
            int idx = u * 256 + tid;
            int r = idx >> 4, c = idx & 15;
            *reinterpret_cast<float4*>(&MnS[r][c * 8]) = bv[u];
        }
#pragma unroll
        for (int u = 0; u < 4; ++u) {
            int idx = u * 256 + tid;
            int r = idx >> 3, c = idx & 7;
            *reinterpret_cast<float4*>(&EbTS[r][c * 8]) = ev[u];
        }
        __syncthreads();
        if (it + 1 < NIT) issue(it + 1);

        // ---- sim + exp + mask (tot / pos / cnt) ----
#pragma unroll
        for (int t = 0; t < 4; ++t) {
            s16x8 b1[4];
#pragma unroll
            for (int ks = 0; ks < 4; ++ks)
                b1[ks] = *reinterpret_cast<const s16x8*>(
                    &MnS[t * 16 + m][ks * 32 + q * 8]);
            f32x4 acc = {0.f, 0.f, 0.f, 0.f};
#pragma unroll
            for (int ks = 0; ks < 4; ++ks)
                acc = __builtin_amdgcn_mfma_f32_16x16x32_bf16(
                    a1[ks], b1[ks], acc, 0, 0, 0);
#pragma unroll
            for (int r = 0; r < 4; ++r) {
                float e = __expf(acc[r] * INV_TAU);
                float avv = __bfloat162float(AdjS[w][q * 4 + r][t * 16 + m]);
                tot[r] += e;
                pos[r] += avv * e;
                cnt[r] += avv;
            }
        }
        // ---- repr += adj @ embX ----
        s16x8 a2[2];
#pragma unroll
        for (int k2 = 0; k2 < 2; ++k2)
            a2[k2] = *reinterpret_cast<const s16x8*>(
                &AdjS[w][m][k2 * 32 + q * 8]);
#pragma unroll
        for (int n = 0; n < 8; ++n) {
            s16x8 b2a = *reinterpret_cast<const s16x8*>(&EbTS[n * 16 + m][q * 8]);
            s16x8 b2b = *reinterpret_cast<const s16x8*>(&EbTS[n * 16 + m][32 + q * 8]);
            racc[n] = __builtin_amdgcn_mfma_f32_16x16x32_bf16(a2[0], b2a, racc[n], 0, 0, 0);
            racc[n] = __builtin_amdgcn_mfma_f32_16x16x32_bf16(a2[1], b2b, racc[n], 0, 0, 0);
        }
    }

    // ---- epilogue: reduce over the 16 col-lanes, merge ----
#pragma unroll
    for (int msk = 1; msk <= 8; msk <<= 1)
#pragma unroll
        for (int r = 0; r < 4; ++r) {
            tot[r] += __shfl_xor(tot[r], msk);
            pos[r] += __shfl_xor(pos[r], msk);
            cnt[r] += __shfl_xor(cnt[r], msk);
        }
    if (m == 0) {
        float* TOT = half ? FPtot : FMtot;
        float* POS = half ? FPpos : FMpos;
        float* CNT = half ? cntP : cntF;
#pragma unroll
        for (int r = 0; r < 4; ++r) {
            int row = row0 + w * 16 + q * 4 + r;
            atomicAdd(&TOT[row], tot[r]);
            atomicAdd(&POS[row], pos[r]);
            atomicAdd(&CNT[row], cnt[r]);
        }
    }
    // repr: pair adjacent d-columns across even/odd lanes -> pk-bf16 atomic
    __hip_bfloat16* rbase = reprB + half * DD;
#pragma unroll
    for (int n = 0; n < 8; ++n)
#pragma unroll
        for (int r = 0; r < 4; ++r) {
            float v = racc[n][r];
            float vp = __shfl_xor(v, 1);
            if ((m & 1) == 0) {
                union { unsigned u; __hip_bfloat162 h; } pk;
                pk.h.x = __float2bfloat16(v);
                pk.h.y = __float2bfloat16(vp);
                const int row = row0 + w * 16 + q * 4 + r;
                __hip_bfloat16* p = rbase + (size_t)row * 256 + n * 16 + m;
                asm volatile("global_atomic_pk_add_bf16 %0, %1, off"
                             :: "v"(p), "v"(pk.u) : "memory");
            }
        }
}

// ------- Kernel 3: MLP from bf16 repr partials (divide + repack on the fly) -
__global__ __launch_bounds__(256) void k_mlp2(
        const __hip_bfloat16* __restrict__ reprB,
        const float* __restrict__ cntF, const float* __restrict__ cntP,
        const __hip_bfloat16* __restrict__ W1tb,
        const float* __restrict__ b1, const float* __restrict__ W2,
        float* __restrict__ z) {
    const int tid = threadIdx.x, w = tid >> 6, lane = tid & 63;
    const int m = lane & 15, q = lane >> 4;
    const int unit = blockIdx.x * 4 + w;             // 0..3071
    const int rb = (unit >> 3) * 16, n0 = (unit & 7) * 16;
    const int row = rb + m;
    const float invF = 1.0f / fmaxf(cntF[row], 1.0f);
    const float invP = 1.0f / fmaxf(cntP[row], 1.0f);
    const __hip_bfloat16* rrow = reprB + (size_t)row * 256;
    f32x4 acc = {0.f, 0.f, 0.f, 0.f};
#pragma unroll
    for (int ks = 0; ks < 8; ++ks) {
        const int k0 = ks * 32 + q * 8;
        const float inv = (k0 < 128) ? invF : invP;
        union { s16x8 v; __hip_bfloat16 h[8]; } ua, ub;
        ub.v = *reinterpret_cast<const s16x8*>(rrow + k0);
#pragma unroll
        for (int e = 0; e < 8; ++e)
            ua.h[e] = __float2bfloat16(__bfloat162float(ub.h[e]) * inv);
        s16x8 bb = *reinterpret_cast<const s16x8*>(
            W1tb + (size_t)(n0 + m) * 256 + k0);
        acc = __builtin_amdgcn_mfma_f32_16x16x32_bf16(ua.v, bb, acc, 0, 0, 0);
    }
    const int n = n0 + m;
    float bias = b1[n], w20 = W2[2 * n], w21 = W2[2 * n + 1];
#pragma unroll
    for (int r = 0; r < 4; ++r) {
        float h = fmaxf(acc[r] + bias, 0.f);
        float p0 = h * w20, p1 = h * w21;
#pragma unroll
        for (int msk = 1; msk <= 8; msk <<= 1) {
            p0 += __shfl_xor(p0, msk);
            p1 += __shfl_xor(p1, msk);
        }
        if (m == 0) {
            int orow = rb + q * 4 + r;
            atomicAdd(&z[2 * orow], p0);
            atomicAdd(&z[2 * orow + 1], p1);
        }
    }
}

// ------- Kernel 4: softmax weights + loss (one atomic per block) -----------
__global__ void k_loss(const float* __restrict__ z, const float* __restrict__ b2,
                       const float* __restrict__ FMpos, const float* __restrict__ FPpos,
                       const float* __restrict__ FMtot, const float* __restrict__ FPtot,
                       const float* __restrict__ cntF, const float* __restrict__ cntP,
                       float* __restrict__ out) {
    __shared__ float red[4];
    const int tid = threadIdx.x;
    const int lane = tid & 63, wv = tid >> 6;
    const int row = blockIdx.x * 256 + tid;
    float z0 = z[row * 2] + b2[0], z1 = z[row * 2 + 1] + b2[1];
    float mx = fmaxf(z0, z1);
    float e0 = expf(z0 - mx), e1 = expf(z1 - mx);
    float inv = 1.0f / (e0 + e1);
    float w0 = e0 * inv, w1 = e1 * inv;
    out[1 + row * 2 + 0] = w0;
    out[1 + row * 2 + 1] = w1;
    float wp = w0 * FMpos[row] + w1 * FPpos[row];
    float wn = w0 * (FMtot[row] - FMpos[row]) + w1 * (FPtot[row] - FPpos[row]);
    float nei = fmaxf(cntF[row] + cntP[row], 1.0f);
    float ratio = wp / (wp + wn) / nei;
    ratio = fmaxf(ratio, 1e-10f);
    float term = -logf(ratio);
#pragma unroll
    for (int msk = 1; msk <= 32; msk <<= 1) term += __shfl_xor(term, msk);
    if (lane == 0) red[wv] = term;
    __syncthreads();
    if (tid == 0)
        atomicAdd(out, (red[0] + red[1] + red[2] + red[3]) * (1.0f / NN));
}

extern "C" void kernel_launch(void* const* d_in, const int* in_sizes, int n_in,
                              void* d_out, int out_size, void* d_ws, size_t ws_size,
                              hipStream_t stream) {
    const float* embF   = (const float*)d_in[0];
    const float* embM   = (const float*)d_in[1];
    const float* embP   = (const float*)d_in[2];
    const float* FM_adj = (const float*)d_in[3];
    const float* FP_adj = (const float*)d_in[4];
    const float* W1     = (const float*)d_in[5];
    const float* b1     = (const float*)d_in[6];
    const float* W2     = (const float*)d_in[7];
    const float* b2     = (const float*)d_in[8];
    float* out = (float*)d_out;

    // workspace layout -- total 11,272,192 B (< proven 11,321,344 B budget)
    float* ws = (float*)d_ws;
    float* FMtot = ws;                         // N   (atomic)
    float* FPtot = FMtot + NN;                 // N   (atomic)
    float* zbuf  = FPtot + NN;                 // 2N  (atomic)
    float* FMpos = zbuf + 2 * NN;              // N   (atomic)
    float* FPpos = FMpos + NN;                 // N   (atomic)
    float* cntF  = FPpos + NN;                 // N   (atomic)
    float* cntP  = cntF + NN;                  // N   (atomic)
    __hip_bfloat16* reprB = (__hip_bfloat16*)(cntP + NN);  // N*256 bf16 (atomic)
    __hip_bfloat16* Fnb  = reprB + (size_t)NN * 256;
    __hip_bfloat16* Mnb  = Fnb + (size_t)NN * DD;
    __hip_bfloat16* Pnb  = Mnb + (size_t)NN * DD;
    __hip_bfloat16* EbTM = Pnb + (size_t)NN * DD;
    __hip_bfloat16* EbTP = EbTM + (size_t)NN * DD;
    __hip_bfloat16* W1tb = EbTP + (size_t)NN * DD;

    hipMemsetAsync(ws, 0, (size_t)8 * NN * sizeof(float)
                           + (size_t)NN * 256 * sizeof(__hip_bfloat16), stream);
    hipMemsetAsync(d_out, 0, sizeof(float), stream);

    k_normalize<<<dim3(1536, 6), 256, 0, stream>>>(embF, embM, embP, W1,
                                                   Fnb, Mnb, Pnb,
                                                   EbTM, EbTP, W1tb);
    k_main<<<dim3(96 * RJCB * 2), 256, 0, stream>>>(FM_adj, FP_adj,
                                                    Fnb, Mnb, Pnb, EbTM, EbTP,
                                                    reprB,
                                                    FMpos, FPpos, FMtot, FPtot,
                                                    cntF, cntP);
    k_mlp2<<<dim3(768), 256, 0, stream>>>(reprB, cntF, cntP, W1tb, b1, W2, zbuf);
    k_loss<<<dim3(NN / 256), 256, 0, stream>>>(zbuf, b2, FMpos, FPpos,
                                               FMtot, FPtot, cntF, cntP, out);
}

// Round 4
// 379.333 us; speedup vs baseline: 1.4266x; 1.0105x over previous
//
#include <hip/hip_runtime.h>
#include <hip/hip_bf16.h>

#define NN 6144
#define DD 128
#define PBL 136         // padded LDS row stride (bf16 elems) -> balanced banks
#define INV_TAU 10.0f

typedef __attribute__((ext_vector_type(4))) float f32x4;
typedef __attribute__((ext_vector_type(8))) short s16x8;

__device__ __forceinline__ void ld4_async(const float4* p, float4& d) {
    asm volatile("global_load_dwordx4 %0, %1, off" : "=v"(d) : "v"(p));
}
__device__ __forceinline__ void vm_wait0() {
    asm volatile("s_waitcnt vmcnt(0)" ::: "memory");
}

// ---- Kernel 1: L2 normalize -> fp32 Fn, bf16 copies, inv-norms; +W1 prep --
__global__ void k_normalize(const float* __restrict__ embF,
                            const float* __restrict__ embM,
                            const float* __restrict__ embP,
                            const float* __restrict__ W1,
                            float* __restrict__ Fn,
                            float* __restrict__ rnM, float* __restrict__ rnP,
                            __hip_bfloat16* __restrict__ Fnb,
                            __hip_bfloat16* __restrict__ Mnb,
                            __hip_bfloat16* __restrict__ Pnb,
                            __hip_bfloat16* __restrict__ W1tb) {
    int which = blockIdx.y;
    if (which == 3) {                 // W1 (256x128) -> bf16 W1^T (128x256)
        if (blockIdx.x < 128) {
            int n = blockIdx.x, c = threadIdx.x;
            W1tb[n * 256 + c] = __float2bfloat16(W1[c * DD + n]);
        }
        return;
    }
    const float* src = which == 0 ? embF : (which == 1 ? embM : embP);
    __hip_bfloat16* dstb = which == 0 ? Fnb : (which == 1 ? Mnb : Pnb);
    int wave = threadIdx.x >> 6, lane = threadIdx.x & 63;
    int row = blockIdx.x * 4 + wave;
    float2 v = reinterpret_cast<const float2*>(src + (size_t)row * DD)[lane];
    float s = v.x * v.x + v.y * v.y;
#pragma unroll
    for (int m = 1; m <= 32; m <<= 1) s += __shfl_xor(s, m);
    float inv = 1.0f / fmaxf(sqrtf(s), 1e-12f);
    float2 o; o.x = v.x * inv; o.y = v.y * inv;
    if (which == 0)
        reinterpret_cast<float2*>(Fn + (size_t)row * DD)[lane] = o;
    if (lane == 0) {
        if (which == 1) rnM[row] = inv;
        if (which == 2) rnP[row] = inv;
    }
    __hip_bfloat162 ob;
    ob.x = __float2bfloat16(o.x);
    ob.y = __float2bfloat16(o.y);
    reinterpret_cast<__hip_bfloat162*>(dstb + (size_t)row * DD)[lane] = ob;
}

// ---------- scan+gather body: one wave per (row, half) ---------------------
// scan: ballot-compaction of the fp32 adjacency row (24 coalesced dwordx4,
//       8 in flight) -> u16 neighbor list in LDS + exact count. No barriers.
// gather: 4-slot pipelined float2 row loads + fp32 dot + shfl reduce + expf.
// Wave owns the row -> featb/pos/cnt written directly, zero atomics.
__device__ __forceinline__ void scan_body(
        int s, char* smem,
        const float* __restrict__ FM_adj, const float* __restrict__ FP_adj,
        const float* __restrict__ embM, const float* __restrict__ embP,
        const float* __restrict__ Fn,
        const float* __restrict__ rnM, const float* __restrict__ rnP,
        __hip_bfloat16* __restrict__ featb,
        float* __restrict__ FMpos, float* __restrict__ FPpos,
        float* __restrict__ cntF, float* __restrict__ cntP) {
    const int tid = threadIdx.x, w = tid >> 6, lane = tid & 63;
    unsigned short* listS = reinterpret_cast<unsigned short*>(smem) + w * 128;
    const int unit = s * 4 + w;
    const int row = unit >> 1, h = unit & 1;
    const float* adj  = h ? FP_adj : FM_adj;
    const float* embX = h ? embP : embM;
    const float* RN   = h ? rnP : rnM;
    const unsigned long long lt = (1ull << lane) - 1ull;

    float2 f2 = reinterpret_cast<const float2*>(Fn + (size_t)row * DD)[lane];
    const float4* ar = reinterpret_cast<const float4*>(adj + (size_t)row * NN);

    int cnt = 0;
    auto scan4 = [&](const float4& v, int k) {
        unsigned long long b;
        int base = k * 256 + lane * 4;
        b = __ballot(v.x != 0.f);
        if (v.x != 0.f) { int p = cnt + (int)__popcll(b & lt); if (p < 128) listS[p] = (unsigned short)base; }
        cnt += (int)__popcll(b);
        b = __ballot(v.y != 0.f);
        if (v.y != 0.f) { int p = cnt + (int)__popcll(b & lt); if (p < 128) listS[p] = (unsigned short)(base + 1); }
        cnt += (int)__popcll(b);
        b = __ballot(v.z != 0.f);
        if (v.z != 0.f) { int p = cnt + (int)__popcll(b & lt); if (p < 128) listS[p] = (unsigned short)(base + 2); }
        cnt += (int)__popcll(b);
        b = __ballot(v.w != 0.f);
        if (v.w != 0.f) { int p = cnt + (int)__popcll(b & lt); if (p < 128) listS[p] = (unsigned short)(base + 3); }
        cnt += (int)__popcll(b);
    };

    float4 va0 = ar[0 * 64 + lane], va1 = ar[1 * 64 + lane];
    float4 va2 = ar[2 * 64 + lane], va3 = ar[3 * 64 + lane];
    for (int kb = 0; kb < 24; kb += 8) {
        float4 vb0 = ar[(kb + 4) * 64 + lane], vb1 = ar[(kb + 5) * 64 + lane];
        float4 vb2 = ar[(kb + 6) * 64 + lane], vb3 = ar[(kb + 7) * 64 + lane];
        scan4(va0, kb + 0); scan4(va1, kb + 1);
        scan4(va2, kb + 2); scan4(va3, kb + 3);
        if (kb + 8 < 24) {
            va0 = ar[(kb + 8) * 64 + lane];  va1 = ar[(kb + 9) * 64 + lane];
            va2 = ar[(kb + 10) * 64 + lane]; va3 = ar[(kb + 11) * 64 + lane];
        }
        scan4(vb0, kb + 4); scan4(vb1, kb + 5);
        scan4(vb2, kb + 6); scan4(vb3, kb + 7);
    }

    asm volatile("s_waitcnt lgkmcnt(0)" ::: "memory");   // list visible to own wave
    const int K = cnt < 128 ? cnt : 128;
    const float2* ex = reinterpret_cast<const float2*>(embX);
    float2 e0 = {0.f, 0.f}, e1 = {0.f, 0.f}, e2 = {0.f, 0.f}, e3 = {0.f, 0.f};
    float rr0 = 0.f, rr1 = 0.f, rr2 = 0.f, rr3 = 0.f;
#define PREF(i, E, R) if ((i) < K) { int j = listS[(i)]; E = ex[(size_t)j * 64 + lane]; R = RN[j]; }
    PREF(0, e0, rr0) PREF(1, e1, rr1) PREF(2, e2, rr2) PREF(3, e3, rr3)
    float2 racc = {0.f, 0.f};
    float wsum = 0.f;
    for (int kk = 0; kk < K; kk += 4) {
#define STEP(i, E, R)                                                        \
        if (kk + (i) < K) {                                                  \
            float2 ev = E; float rv = R;                                     \
            PREF(kk + (i) + 4, E, R)                                         \
            float d = f2.x * ev.x + f2.y * ev.y;                             \
            d += __shfl_xor(d, 1);  d += __shfl_xor(d, 2);                   \
            d += __shfl_xor(d, 4);  d += __shfl_xor(d, 8);                   \
            d += __shfl_xor(d, 16); d += __shfl_xor(d, 32);                  \
            racc.x += ev.x; racc.y += ev.y;                                  \
            wsum += __expf(d * rv * INV_TAU);                                \
        }
        STEP(0, e0, rr0) STEP(1, e1, rr1) STEP(2, e2, rr2) STEP(3, e3, rr3)
    }
#undef STEP
#undef PREF

    float invK = 1.0f / fmaxf((float)cnt, 1.0f);
    __hip_bfloat162 ob;
    ob.x = __float2bfloat16(racc.x * invK);
    ob.y = __float2bfloat16(racc.y * invK);
    reinterpret_cast<__hip_bfloat162*>(featb + (size_t)row * 256 + h * DD)[lane] = ob;
    if (lane == 0) {
        (h ? FPpos : FMpos)[row] = wsum;
        (h ? cntP : cntF)[row] = (float)cnt;
    }
}

// ---------- dense body: exp row-sum over one (128-row, 384-col) tile -------
__device__ __forceinline__ void dense_body(
        int unit, char* smem,
        const __hip_bfloat16* __restrict__ Fnb,
        const __hip_bfloat16* __restrict__ Mnb,
        const __hip_bfloat16* __restrict__ Pnb,
        float* __restrict__ FMtot, float* __restrict__ FPtot) {
    __hip_bfloat16 (*Bs)[PBL] = (__hip_bfloat16(*)[PBL])smem;   // 64 x PBL
    const int bx = unit % 48, by = (unit / 48) % 16, half = unit / 768;
    const __hip_bfloat16* Bnb = half ? Pnb : Mnb;
    float* TOT = half ? FPtot : FMtot;
    const int tid = threadIdx.x;
    const int w = tid >> 6, lane = tid & 63;
    const int m = lane & 15, q = lane >> 4;
    const int rb = bx * 128 + w * 32;
    const int j0 = by * (NN / 16);                   // 384-col strip

    s16x8 a[2][4];
#pragma unroll
    for (int g = 0; g < 2; ++g)
#pragma unroll
        for (int ks = 0; ks < 4; ++ks)
            a[g][ks] = *reinterpret_cast<const s16x8*>(
                Fnb + (size_t)(rb + g * 16 + m) * DD + ks * 32 + q * 8);

    float4 s0, s1, s2, s3;
    auto issue = [&](int jc) {
        const float4* gp = reinterpret_cast<const float4*>(Bnb + (size_t)jc * DD);
        ld4_async(gp + tid,       s0);
        ld4_async(gp + 256 + tid, s1);
        ld4_async(gp + 512 + tid, s2);
        ld4_async(gp + 768 + tid, s3);
    };
    auto stash = [&](int idx, const float4& v) {
        *reinterpret_cast<float4*>(&Bs[idx >> 4][(idx & 15) * 8]) = v;
    };

    issue(j0);
    float tot[2][4] = {{0.f, 0.f, 0.f, 0.f}, {0.f, 0.f, 0.f, 0.f}};
    for (int it = 0; it < 6; ++it) {
        vm_wait0();
        __syncthreads();
        stash(tid, s0);
        stash(256 + tid, s1);
        stash(512 + tid, s2);
        stash(768 + tid, s3);
        __syncthreads();
        if (it + 1 < 6) issue(j0 + (it + 1) * 64);
#pragma unroll
        for (int t = 0; t < 4; ++t) {
            s16x8 b[4];
#pragma unroll
            for (int ks = 0; ks < 4; ++ks)
                b[ks] = *reinterpret_cast<const s16x8*>(
                    &Bs[t * 16 + m][ks * 32 + q * 8]);
#pragma unroll
            for (int g = 0; g < 2; ++g) {
                f32x4 acc = {0.f, 0.f, 0.f, 0.f};
#pragma unroll
                for (int ks = 0; ks < 4; ++ks)
                    acc = __builtin_amdgcn_mfma_f32_16x16x32_bf16(
                        a[g][ks], b[ks], acc, 0, 0, 0);
#pragma unroll
                for (int r = 0; r < 4; ++r)
                    tot[g][r] += __expf(acc[r] * INV_TAU);
            }
        }
    }
#pragma unroll
    for (int msk = 1; msk <= 8; msk <<= 1)
#pragma unroll
        for (int g = 0; g < 2; ++g)
#pragma unroll
            for (int r = 0; r < 4; ++r)
                tot[g][r] += __shfl_xor(tot[g][r], msk);
    if (m == 0)
#pragma unroll
        for (int g = 0; g < 2; ++g)
#pragma unroll
            for (int r = 0; r < 4; ++r)
                atomicAdd(&TOT[rb + g * 16 + q * 4 + r], tot[g][r]);
}

// ------- Kernel 2: co-scheduled scan/gather + dense-MFMA -------------------
__global__ __launch_bounds__(256) void k_main(
        const float* __restrict__ FM_adj, const float* __restrict__ FP_adj,
        const float* __restrict__ embM, const float* __restrict__ embP,
        const float* __restrict__ Fn,
        const float* __restrict__ rnM, const float* __restrict__ rnP,
        const __hip_bfloat16* __restrict__ Fnb,
        const __hip_bfloat16* __restrict__ Mnb,
        const __hip_bfloat16* __restrict__ Pnb,
        __hip_bfloat16* __restrict__ featb,
        float* __restrict__ FMpos, float* __restrict__ FPpos,
        float* __restrict__ FMtot, float* __restrict__ FPtot,
        float* __restrict__ cntF, float* __restrict__ cntP) {
    __shared__ char smem[64 * PBL * 2];              // 17408 B (union)
    const int b = blockIdx.x;
    const int u = b / 3, r = b - u * 3;
    if (r == 2)
        dense_body(u, smem, Fnb, Mnb, Pnb, FMtot, FPtot);
    else
        scan_body(u * 2 + r, smem, FM_adj, FP_adj, embM, embP,
                  Fn, rnM, rnP, featb, FMpos, FPpos, cntF, cntP);
}

// ------- Kernel 3: MLP hidden+logit partials via MFMA ----------------------
__global__ __launch_bounds__(256) void k_mlp2(
        const __hip_bfloat16* __restrict__ featb,
        const __hip_bfloat16* __restrict__ W1tb,
        const float* __restrict__ b1, const float* __restrict__ W2,
        float* __restrict__ z) {
    const int tid = threadIdx.x, w = tid >> 6, lane = tid & 63;
    const int m = lane & 15, q = lane >> 4;
    const int unit = blockIdx.x * 4 + w;             // 0..3071
    const int rb = (unit >> 3) * 16, n0 = (unit & 7) * 16;
    f32x4 acc = {0.f, 0.f, 0.f, 0.f};
#pragma unroll
    for (int ks = 0; ks < 8; ++ks) {
        s16x8 a = *reinterpret_cast<const s16x8*>(
            featb + (size_t)(rb + m) * 256 + ks * 32 + q * 8);
        s16x8 b = *reinterpret_cast<const s16x8*>(
            W1tb + (size_t)(n0 + m) * 256 + ks * 32 + q * 8);
        acc = __builtin_amdgcn_mfma_f32_16x16x32_bf16(a, b, acc, 0, 0, 0);
    }
    const int n = n0 + m;
    float bias = b1[n], w20 = W2[2 * n], w21 = W2[2 * n + 1];
#pragma unroll
    for (int r = 0; r < 4; ++r) {
        float h = fmaxf(acc[r] + bias, 0.f);
        float p0 = h * w20, p1 = h * w21;
#pragma unroll
        for (int msk = 1; msk <= 8; msk <<= 1) {
            p0 += __shfl_xor(p0, msk);
            p1 += __shfl_xor(p1, msk);
        }
        if (m == 0) {
            int row = rb + q * 4 + r;
            atomicAdd(&z[2 * row], p0);
            atomicAdd(&z[2 * row + 1], p1);
        }
    }
}

// ------- Kernel 4: softmax weights + loss (one atomic per block) -----------
__global__ void k_loss(const float* __restrict__ z, const float* __restrict__ b2,
                       const float* __restrict__ FMpos, const float* __restrict__ FPpos,
                       const float* __restrict__ FMtot, const float* __restrict__ FPtot,
                       const float* __restrict__ cntF, const float* __restrict__ cntP,
                       float* __restrict__ out) {
    __shared__ float red[4];
    const int tid = threadIdx.x;
    const int lane = tid & 63, wv = tid >> 6;
    const int row = blockIdx.x * 256 + tid;
    float z0 = z[row * 2] + b2[0], z1 = z[row * 2 + 1] + b2[1];
    float mx = fmaxf(z0, z1);
    float e0 = expf(z0 - mx), e1 = expf(z1 - mx);
    float inv = 1.0f / (e0 + e1);
    float w0 = e0 * inv, w1 = e1 * inv;
    out[1 + row * 2 + 0] = w0;
    out[1 + row * 2 + 1] = w1;
    float wp = w0 * FMpos[row] + w1 * FPpos[row];
    float wn = w0 * (FMtot[row] - FMpos[row]) + w1 * (FPtot[row] - FPpos[row]);
    float nei = fmaxf(cntF[row] + cntP[row], 1.0f);
    float ratio = wp / (wp + wn) / nei;
    ratio = fmaxf(ratio, 1e-10f);
    float term = -logf(ratio);
#pragma unroll
    for (int msk = 1; msk <= 32; msk <<= 1) term += __shfl_xor(term, msk);
    if (lane == 0) red[wv] = term;
    __syncthreads();
    if (tid == 0)
        atomicAdd(out, (red[0] + red[1] + red[2] + red[3]) * (1.0f / NN));
}

extern "C" void kernel_launch(void* const* d_in, const int* in_sizes, int n_in,
                              void* d_out, int out_size, void* d_ws, size_t ws_size,
                              hipStream_t stream) {
    const float* embF   = (const float*)d_in[0];
    const float* embM   = (const float*)d_in[1];
    const float* embP   = (const float*)d_in[2];
    const float* FM_adj = (const float*)d_in[3];
    const float* FP_adj = (const float*)d_in[4];
    const float* W1     = (const float*)d_in[5];
    const float* b1     = (const float*)d_in[6];
    const float* W2     = (const float*)d_in[7];
    const float* b2     = (const float*)d_in[8];
    float* out = (float*)d_out;

    float* ws = (float*)d_ws;
    float* FMtot = ws;                       // N  (atomic -> zeroed)
    float* FPtot = FMtot + NN;               // N  (atomic -> zeroed)
    float* zbuf  = FPtot + NN;               // 2N (atomic -> zeroed)
    float* FMpos = zbuf + 2 * NN;            // N
    float* FPpos = FMpos + NN;               // N
    float* cntF  = FPpos + NN;               // N
    float* cntP  = cntF + NN;                // N
    float* rnM   = cntP + NN;                // N
    float* rnP   = rnM + NN;                 // N
    float* Fn    = rnP + NN;                 // N*D fp32 normalized
    __hip_bfloat16* Fnb = (__hip_bfloat16*)(Fn + (size_t)NN * DD);
    __hip_bfloat16* Mnb = Fnb + (size_t)NN * DD;
    __hip_bfloat16* Pnb = Mnb + (size_t)NN * DD;
    __hip_bfloat16* featb = Pnb + (size_t)NN * DD;       // N*256 bf16
    __hip_bfloat16* W1tb  = featb + (size_t)NN * 256;    // 128*256 bf16

    hipMemsetAsync(FMtot, 0, 4 * NN * sizeof(float), stream);
    hipMemsetAsync(d_out, 0, sizeof(float), stream);

    k_normalize<<<dim3(NN / 4, 4), 256, 0, stream>>>(embF, embM, embP, W1,
                                                     Fn, rnM, rnP,
                                                     Fnb, Mnb, Pnb, W1tb);
    k_main<<<dim3(4608), 256, 0, stream>>>(FM_adj, FP_adj, embM, embP,
                                           Fn, rnM, rnP, Fnb, Mnb, Pnb,
                                           featb, FMpos, FPpos, FMtot, FPtot,
                                           cntF, cntP);
    k_mlp2<<<dim3(768), 256, 0, stream>>>(featb, W1tb, b1, W2, zbuf);
    k_loss<<<dim3(NN / 256), 256, 0, stream>>>(zbuf, b2, FMpos, FPpos,
                                               FMtot, FPtot, cntF, cntP, out);
}